// Round 1
// baseline (61.613 us; speedup 1.0000x reference)
//
#include <hip/hip_runtime.h>
#include <math.h>

#define Bb 64
#define Ll 1024
#define Dd 512
#define Aa 512
#define NEG_INF -1e9f

__device__ __forceinline__ float fast_tanh(float x) {
    // tanh(x) = 1 - 2/(e^{2x}+1); saturates cleanly to +-1 for large |x|
    float e = __expf(2.f * x);
    return 1.f - 2.f / (e + 1.f);
}

// K1: qb[b][a] = dot(decoder_h[b,:], W[a,:]) + bias[a]; vv[a] = g * v[a]/||v||
__global__ __launch_bounds__(512) void k_qb(const float* __restrict__ dh,
                                            const float* __restrict__ W,
                                            const float* __restrict__ bias,
                                            const float* __restrict__ vw,
                                            const float* __restrict__ vg,
                                            float* __restrict__ qb,
                                            float* __restrict__ vv) {
    __shared__ float h[Dd];
    __shared__ float red[8];
    const int b = blockIdx.x;
    const int a = threadIdx.x;
    h[a] = dh[b * Dd + a];

    // weight-norm denominator (redundant per block; cheap)
    float w = vw[a];
    float s = w * w;
    #pragma unroll
    for (int off = 32; off; off >>= 1) s += __shfl_xor(s, off);
    const int wave = a >> 6, lane = a & 63;
    if (lane == 0) red[wave] = s;
    __syncthreads();
    float tot = red[0] + red[1] + red[2] + red[3] + red[4] + red[5] + red[6] + red[7];
    float inv = rsqrtf(tot);
    if (b == 0) vv[a] = vg[0] * w * inv;

    float acc = 0.f;
    const float4* Wr = (const float4*)(W + (size_t)a * Dd);
    #pragma unroll 8
    for (int d4 = 0; d4 < Dd / 4; ++d4) {
        float4 wq = Wr[d4];
        int d = d4 * 4;
        acc = fmaf(wq.x, h[d + 0], acc);
        acc = fmaf(wq.y, h[d + 1], acc);
        acc = fmaf(wq.z, h[d + 2], acc);
        acc = fmaf(wq.w, h[d + 3], acc);
    }
    qb[b * Aa + a] = acc + bias[a];
}

// K2: p[b][l] = sigmoid-with-mask of energy(b,l); one wave per l, 4 l per wave
__global__ __launch_bounds__(256) void k_energy(const float* __restrict__ key,
                                                const float* __restrict__ noise,
                                                const float* __restrict__ mask,
                                                const float* __restrict__ qb,
                                                const float* __restrict__ vv,
                                                const float* __restrict__ vbias,
                                                const float* __restrict__ r,
                                                float* __restrict__ p) {
    __shared__ float qs[Aa];
    __shared__ float vs[Aa];
    const int b = blockIdx.y;
    const int l0 = blockIdx.x * 16;
    const int tid = threadIdx.x;
    qs[tid]       = qb[b * Aa + tid];
    qs[tid + 256] = qb[b * Aa + tid + 256];
    vs[tid]       = vv[tid];
    vs[tid + 256] = vv[tid + 256];
    __syncthreads();

    const int wave = tid >> 6, lane = tid & 63;
    const float c0 = vbias[0] + r[0];

    #pragma unroll
    for (int il = 0; il < 4; ++il) {
        const int l = l0 + wave * 4 + il;
        const float4* kp = (const float4*)(key + ((size_t)b * Ll + l) * Aa);
        float4 ka = kp[lane];
        float4 kb = kp[lane + 64];
        const int a0 = lane * 4;
        const int a1 = 256 + lane * 4;
        float sum =
            fast_tanh(qs[a0 + 0] + ka.x) * vs[a0 + 0] +
            fast_tanh(qs[a0 + 1] + ka.y) * vs[a0 + 1] +
            fast_tanh(qs[a0 + 2] + ka.z) * vs[a0 + 2] +
            fast_tanh(qs[a0 + 3] + ka.w) * vs[a0 + 3] +
            fast_tanh(qs[a1 + 0] + kb.x) * vs[a1 + 0] +
            fast_tanh(qs[a1 + 1] + kb.y) * vs[a1 + 1] +
            fast_tanh(qs[a1 + 2] + kb.z) * vs[a1 + 2] +
            fast_tanh(qs[a1 + 3] + kb.w) * vs[a1 + 3];
        #pragma unroll
        for (int off = 32; off; off >>= 1) sum += __shfl_xor(sum, off);
        if (lane == 0) {
            const float m = mask[b * Ll + l];
            float e = (m > 0.f) ? (sum + c0) : NEG_INF;
            float z = e + noise[b * Ll + l];
            float pv = 1.f / (1.f + __expf(-z));
            float mn = (l == Ll - 1) ? 0.f : mask[b * Ll + l + 1];
            float em = m * (1.f - mn);
            if (em > 0.f) pv = em;
            p[b * Ll + l] = pv;
        }
    }
}

// K3: alpha[b][l] = p * scan(x_j = a_j x_{j-1} + prev_att_j), a_j = 1-p_{j-1}
__global__ __launch_bounds__(64) void k_scan(const float* __restrict__ p,
                                             const float* __restrict__ prev,
                                             float* __restrict__ alpha) {
    const int b = blockIdx.x;
    const int lane = threadIdx.x;
    const int j0 = lane * 16;
    const float* pr = p + (size_t)b * Ll;
    const float* pa = prev + (size_t)b * Ll;

    // local segment composition: x_out = Ax * x_in + Bx
    float Ax = 1.f, Bx = 0.f;
    #pragma unroll
    for (int k = 0; k < 16; ++k) {
        const int j = j0 + k;
        float aj = (j == 0) ? 1.f : (1.f - pr[j - 1]);
        Bx = fmaf(aj, Bx, pa[j]);
        Ax *= aj;
    }
    // inclusive Hillis-Steele scan over affine pairs across the wave
    #pragma unroll
    for (int off = 1; off < 64; off <<= 1) {
        float pA = __shfl_up(Ax, off);
        float pB = __shfl_up(Bx, off);
        if (lane >= off) {
            Bx = fmaf(Ax, pB, Bx);
            Ax *= pA;
        }
    }
    float xin = __shfl_up(Bx, 1);
    if (lane == 0) xin = 0.f;

    float x = xin;
    #pragma unroll
    for (int k = 0; k < 16; ++k) {
        const int j = j0 + k;
        float aj = (j == 0) ? 1.f : (1.f - pr[j - 1]);
        x = fmaf(aj, x, pa[j]);
        alpha[b * Ll + j] = pr[j] * x;
    }
}

extern "C" void kernel_launch(void* const* d_in, const int* in_sizes, int n_in,
                              void* d_out, int out_size, void* d_ws, size_t ws_size,
                              hipStream_t stream) {
    const float* dh    = (const float*)d_in[0];   // decoder_h [B,D]
    const float* key   = (const float*)d_in[1];   // key [B,L,A]
    // d_in[2] encoder_outputs — unused by the reference
    const float* prev  = (const float*)d_in[3];   // prev_att [B,L]
    const float* noise = (const float*)d_in[4];   // noise [B,L]
    const float* mask  = (const float*)d_in[5];   // mask [B,L]
    const float* W     = (const float*)d_in[6];   // W [A,D]
    const float* bias  = (const float*)d_in[7];   // b [A]
    const float* vw    = (const float*)d_in[8];   // v_weight [1,A]
    const float* vg    = (const float*)d_in[9];   // v_g [1]
    const float* vb    = (const float*)d_in[10];  // v_bias [1]
    const float* r     = (const float*)d_in[11];  // r [1]
    float* out = (float*)d_out;

    float* ws = (float*)d_ws;
    float* vv = ws;                    // 512 floats
    float* qb = ws + Aa;               // 64*512 floats
    float* p  = ws + Aa + Bb * Aa;     // 64*1024 floats

    k_qb<<<Bb, 512, 0, stream>>>(dh, W, bias, vw, vg, qb, vv);
    k_energy<<<dim3(Ll / 16, Bb), 256, 0, stream>>>(key, noise, mask, qb, vv, vb, r, p);
    k_scan<<<Bb, 64, 0, stream>>>(p, prev, out);
}

// Round 2
// 58.573 us; speedup vs baseline: 1.0519x; 1.0519x over previous
//
#include <hip/hip_runtime.h>
#include <math.h>

#define Bb 64
#define Ll 1024
#define Dd 512
#define Aa 512
#define NEG_INF -1e9f

#define LOG2E  1.4426950408889634f
#define LOG2E2 2.8853901617526703f   // 2*log2(e)

__device__ __forceinline__ float fast_exp2(float x) { return __builtin_amdgcn_exp2f(x); }
__device__ __forceinline__ float fast_rcp(float x)  { return __builtin_amdgcn_rcpf(x); }

// K1: qb[b][a] = dot(decoder_h[b,:], W[a,:]) + bias[a]
//     vv2[a] = 2 * g * v[a]/||v||   (block b==0 also writes scal[0] = sum_a vv[a] + vbias + r)
__global__ __launch_bounds__(512) void k_qb(const float* __restrict__ dh,
                                            const float* __restrict__ W,
                                            const float* __restrict__ bias,
                                            const float* __restrict__ vw,
                                            const float* __restrict__ vg,
                                            const float* __restrict__ vb,
                                            const float* __restrict__ r,
                                            float* __restrict__ qb,
                                            float* __restrict__ vv2,
                                            float* __restrict__ scal) {
    __shared__ float h[Dd];
    __shared__ float red[8];
    const int b = blockIdx.x;
    const int a = threadIdx.x;
    h[a] = dh[b * Dd + a];

    // ||v||^2 (redundant per block; cheap)
    float w = vw[a];
    float s = w * w;
    #pragma unroll
    for (int off = 32; off; off >>= 1) s += __shfl_xor(s, off);
    const int wave = a >> 6, lane = a & 63;
    if (lane == 0) red[wave] = s;
    __syncthreads();
    float tot = red[0] + red[1] + red[2] + red[3] + red[4] + red[5] + red[6] + red[7];
    float inv = rsqrtf(tot);
    float vva = vg[0] * w * inv;

    float acc = 0.f;
    const float4* Wr = (const float4*)(W + (size_t)a * Dd);
    #pragma unroll 8
    for (int d4 = 0; d4 < Dd / 4; ++d4) {
        float4 wq = Wr[d4];
        int d = d4 * 4;
        acc = fmaf(wq.x, h[d + 0], acc);
        acc = fmaf(wq.y, h[d + 1], acc);
        acc = fmaf(wq.z, h[d + 2], acc);
        acc = fmaf(wq.w, h[d + 3], acc);
    }
    qb[b * Aa + a] = acc + bias[a];

    if (b == 0) {
        vv2[a] = 2.f * vva;
        float s2 = vva;
        #pragma unroll
        for (int off = 32; off; off >>= 1) s2 += __shfl_xor(s2, off);
        __syncthreads();                  // red[] reuse: all reads of tot done
        if (lane == 0) red[wave] = s2;
        __syncthreads();
        if (a == 0) {
            float sv = red[0] + red[1] + red[2] + red[3] + red[4] + red[5] + red[6] + red[7];
            scal[0] = sv + vb[0] + r[0];  // sum_a vv[a] + vbias + r
        }
    }
}

// K2: p[b][l] = masked sigmoid(energy+noise); one wave per 4 l, no LDS.
// energy = scal0 - sum_a vv2[a] * rcp(exp2((q[a]+k[a])*2log2e) + 1)
__global__ __launch_bounds__(256) void k_energy(const float* __restrict__ key,
                                                const float* __restrict__ noise,
                                                const float* __restrict__ mask,
                                                const float* __restrict__ qb,
                                                const float* __restrict__ vv2,
                                                const float* __restrict__ scal,
                                                float* __restrict__ p) {
    const int b = blockIdx.y;
    const int l0 = blockIdx.x * 16;
    const int tid = threadIdx.x;
    const int wave = tid >> 6, lane = tid & 63;

    const float4* qb4 = (const float4*)(qb + (size_t)b * Aa);
    float4 q0 = qb4[lane];
    float4 q1 = qb4[lane + 64];
    const float4* v4 = (const float4*)vv2;
    const float4 v0 = v4[lane];
    const float4 v1 = v4[lane + 64];
    const float ec = scal[0];

    // pre-scale q by 2*log2(e) so inner loop is a single fma per element
    q0.x *= LOG2E2; q0.y *= LOG2E2; q0.z *= LOG2E2; q0.w *= LOG2E2;
    q1.x *= LOG2E2; q1.y *= LOG2E2; q1.z *= LOG2E2; q1.w *= LOG2E2;

    #pragma unroll
    for (int il = 0; il < 4; ++il) {
        const int l = l0 + wave * 4 + il;
        const float4* kp = (const float4*)(key + ((size_t)b * Ll + l) * Aa);
        float4 ka = kp[lane];
        float4 kb = kp[lane + 64];

        float acc = 0.f;
        acc = fmaf(v0.x, fast_rcp(fast_exp2(fmaf(ka.x, LOG2E2, q0.x)) + 1.f), acc);
        acc = fmaf(v0.y, fast_rcp(fast_exp2(fmaf(ka.y, LOG2E2, q0.y)) + 1.f), acc);
        acc = fmaf(v0.z, fast_rcp(fast_exp2(fmaf(ka.z, LOG2E2, q0.z)) + 1.f), acc);
        acc = fmaf(v0.w, fast_rcp(fast_exp2(fmaf(ka.w, LOG2E2, q0.w)) + 1.f), acc);
        acc = fmaf(v1.x, fast_rcp(fast_exp2(fmaf(kb.x, LOG2E2, q1.x)) + 1.f), acc);
        acc = fmaf(v1.y, fast_rcp(fast_exp2(fmaf(kb.y, LOG2E2, q1.y)) + 1.f), acc);
        acc = fmaf(v1.z, fast_rcp(fast_exp2(fmaf(kb.z, LOG2E2, q1.z)) + 1.f), acc);
        acc = fmaf(v1.w, fast_rcp(fast_exp2(fmaf(kb.w, LOG2E2, q1.w)) + 1.f), acc);

        #pragma unroll
        for (int off = 32; off; off >>= 1) acc += __shfl_xor(acc, off);

        if (lane == 0) {
            const float m = mask[b * Ll + l];
            float e = (m > 0.f) ? (ec - acc) : NEG_INF;
            float z = e + noise[b * Ll + l];
            float pv = fast_rcp(1.f + fast_exp2(-z * LOG2E));
            float mn = (l == Ll - 1) ? 0.f : mask[b * Ll + l + 1];
            float em = m * (1.f - mn);
            if (em > 0.f) pv = em;
            p[b * Ll + l] = pv;
        }
    }
}

// K3: alpha[b][l] = p_l * x_l,  x_j = (1-p_{j-1}) x_{j-1} + prev_j  (x_{-1}=0)
__global__ __launch_bounds__(64) void k_scan(const float* __restrict__ p,
                                             const float* __restrict__ prev,
                                             float* __restrict__ alpha) {
    const int b = blockIdx.x;
    const int lane = threadIdx.x;
    const float4* p4 = (const float4*)(p + (size_t)b * Ll);
    const float4* a4 = (const float4*)(prev + (size_t)b * Ll);

    float pr[16], pa[16];
    #pragma unroll
    for (int k = 0; k < 4; ++k) {
        float4 t = p4[lane * 4 + k];
        pr[k * 4 + 0] = t.x; pr[k * 4 + 1] = t.y; pr[k * 4 + 2] = t.z; pr[k * 4 + 3] = t.w;
        float4 u = a4[lane * 4 + k];
        pa[k * 4 + 0] = u.x; pa[k * 4 + 1] = u.y; pa[k * 4 + 2] = u.z; pa[k * 4 + 3] = u.w;
    }
    float pm1 = __shfl_up(pr[15], 1);   // p[j0-1]
    if (lane == 0) pm1 = 0.f;           // so a_0 = 1

    // local affine composition x_out = Ax * x_in + Bx
    float Ax = 1.f, Bx = 0.f;
    #pragma unroll
    for (int k = 0; k < 16; ++k) {
        float aj = 1.f - ((k == 0) ? pm1 : pr[k - 1]);
        Bx = fmaf(aj, Bx, pa[k]);
        Ax *= aj;
    }
    // inclusive Hillis-Steele scan over affine pairs across the wave
    #pragma unroll
    for (int off = 1; off < 64; off <<= 1) {
        float pA = __shfl_up(Ax, off);
        float pB = __shfl_up(Bx, off);
        if (lane >= off) {
            Bx = fmaf(Ax, pB, Bx);
            Ax *= pA;
        }
    }
    float xin = __shfl_up(Bx, 1);
    if (lane == 0) xin = 0.f;

    float x = xin;
    float out[16];
    #pragma unroll
    for (int k = 0; k < 16; ++k) {
        float aj = 1.f - ((k == 0) ? pm1 : pr[k - 1]);
        x = fmaf(aj, x, pa[k]);
        out[k] = pr[k] * x;
    }
    float4* o4 = (float4*)(alpha + (size_t)b * Ll);
    #pragma unroll
    for (int k = 0; k < 4; ++k) {
        float4 t;
        t.x = out[k * 4 + 0]; t.y = out[k * 4 + 1]; t.z = out[k * 4 + 2]; t.w = out[k * 4 + 3];
        o4[lane * 4 + k] = t;
    }
}

extern "C" void kernel_launch(void* const* d_in, const int* in_sizes, int n_in,
                              void* d_out, int out_size, void* d_ws, size_t ws_size,
                              hipStream_t stream) {
    const float* dh    = (const float*)d_in[0];   // decoder_h [B,D]
    const float* key   = (const float*)d_in[1];   // key [B,L,A]
    // d_in[2] encoder_outputs — unused by the reference
    const float* prev  = (const float*)d_in[3];   // prev_att [B,L]
    const float* noise = (const float*)d_in[4];   // noise [B,L]
    const float* mask  = (const float*)d_in[5];   // mask [B,L]
    const float* W     = (const float*)d_in[6];   // W [A,D]
    const float* bias  = (const float*)d_in[7];   // b [A]
    const float* vw    = (const float*)d_in[8];   // v_weight [1,A]
    const float* vg    = (const float*)d_in[9];   // v_g [1]
    const float* vb    = (const float*)d_in[10];  // v_bias [1]
    const float* r     = (const float*)d_in[11];  // r [1]
    float* out = (float*)d_out;

    float* ws   = (float*)d_ws;
    float* vv2  = ws;                       // 512 floats (=2*vv)
    float* scal = ws + Aa;                  // 1 float (sum vv + vbias + r), padded
    float* qb   = ws + 1024;                // 64*512 floats, 16B-aligned
    float* p    = ws + 1024 + Bb * Aa;      // 64*1024 floats

    k_qb<<<Bb, 512, 0, stream>>>(dh, W, bias, vw, vg, vb, r, qb, vv2, scal);
    k_energy<<<dim3(Ll / 16, Bb), 256, 0, stream>>>(key, noise, mask, qb, vv2, scal, p);
    k_scan<<<Bb, 64, 0, stream>>>(p, prev, out);
}